// Round 12
// baseline (78.402 us; speedup 1.0000x reference)
//
#include <hip/hip_runtime.h>
#include <hip/hip_bf16.h>

// GCN conv: out = mean-aggregate(h over CSR) + bias, h = x @ W (bf16).
// R11: agg_ns2b frozen (3.9TB/s TCC fill wall). gemm: operand-swapped MFMA
// (lane owns node ROW -> 8x 8B cvt_pk stores instead of 32 scalar b16 stores).
// NO NT x-loads (R7 post-mortem: NT no-allocate re-fetches the shared x line
// across the f0/f1 pair -> 2x x traffic). 1563 blocks, pre-converted Wt.

#define NN 100000
#define D 128

using short8 = __attribute__((ext_vector_type(8))) short;
using f32x4 = __attribute__((ext_vector_type(4))) float;
using u32x2 = __attribute__((ext_vector_type(2))) unsigned int;

__device__ __forceinline__ float bf2f(short s) {
  unsigned int u = ((unsigned int)(unsigned short)s) << 16;
  return __builtin_bit_cast(float, u);
}
__device__ __forceinline__ short f2bs(float f) {
  __hip_bfloat16 b = __float2bfloat16(f);
  return *reinterpret_cast<short*>(&b);
}
__device__ __forceinline__ unsigned int pkbf(float lo, float hi) {
  unsigned int r;
  asm("v_cvt_pk_bf16_f32 %0, %1, %2" : "=v"(r) : "v"(lo), "v"(hi));
  return r;
}

// ---------- Kernel 0: Wt[c][k] = bf16(W[k][c]), linear 32KB in ws ----------
__global__ __launch_bounds__(256) void cvt_w(const float* __restrict__ W,
                                             __hip_bfloat16* __restrict__ Wt) {
  int i = blockIdx.x * 256 + threadIdx.x;  // 16384 threads, 1 elem each
  int k = i >> 7, c = i & 127;
  Wt[c * D + k] = __float2bfloat16(W[i]);
}

// ---------- Kernel 1: h[s][n][c] = (x@W)[n][s*64+c], bf16, 2-slice layout ----------
// Swapped MFMA: acc[ct] = mfma(W_frag, x_frag) -> lane (c16,kc) holds node
// r0+c16, cols ct*16 + kc*4 + j (layout verified R7). Epilogue: 8x u32x2.
__global__ __launch_bounds__(256) void gemm_xw_swp(const float* __restrict__ x,
                                                   const __hip_bfloat16* __restrict__ Wt,
                                                   __hip_bfloat16* __restrict__ h) {
  __shared__ __hip_bfloat16 Wl[D][D + 8];  // Wl[col][k], +8 pad
  int tid = threadIdx.x;
#pragma unroll
  for (int i = 0; i < 8; ++i) {
    int e = (tid + i * 256) * 8;  // element offset into Wt (c-major)
    int c = e >> 7, k0 = e & 127;
    short8 v = *reinterpret_cast<const short8*>(Wt + e);
    *reinterpret_cast<short8*>(&Wl[c][k0]) = v;
  }
  __syncthreads();

  int wid = tid >> 6, lane = tid & 63;
  int c16 = lane & 15;
  int kc = lane >> 4;

  const int ntiles = NN / 16;  // 6250 exact
  int t = blockIdx.x * 4 + wid;
  if (t >= ntiles) return;
  int r0 = t * 16;

  const float* xrow = x + (size_t)(r0 + c16) * D + kc * 8;
  short8 a[4];
#pragma unroll
  for (int kk = 0; kk < 4; ++kk) {
    float4 f0 = *reinterpret_cast<const float4*>(xrow + kk * 32);
    float4 f1 = *reinterpret_cast<const float4*>(xrow + kk * 32 + 4);
    a[kk][0] = f2bs(f0.x); a[kk][1] = f2bs(f0.y);
    a[kk][2] = f2bs(f0.z); a[kk][3] = f2bs(f0.w);
    a[kk][4] = f2bs(f1.x); a[kk][5] = f2bs(f1.y);
    a[kk][6] = f2bs(f1.z); a[kk][7] = f2bs(f1.w);
  }

  f32x4 acc[8];
#pragma unroll
  for (int ct = 0; ct < 8; ++ct) acc[ct] = (f32x4)(0.0f);

#pragma unroll
  for (int kk = 0; kk < 4; ++kk) {
#pragma unroll
    for (int ct = 0; ct < 8; ++ct) {
      short8 b = *reinterpret_cast<const short8*>(&Wl[ct * 16 + c16][kk * 32 + kc * 8]);
      // swapped: W-frag as A, x-frag as B -> D[m=Wcol][n=node]
      acc[ct] = __builtin_amdgcn_mfma_f32_16x16x32_bf16(b, a[kk], acc[ct], 0, 0, 0);
    }
  }

  // lane owns node r0+c16; for each ct: slice s=ct>>2, in-slice cols
  // (ct&3)*16 + kc*4 + {0..3} -> one 8B store.
  int node = r0 + c16;
#pragma unroll
  for (int ct = 0; ct < 8; ++ct) {
    size_t sb = (size_t)(ct >> 2) * NN;
    __hip_bfloat16* hp = h + (sb + node) * 64 + (ct & 3) * 16 + kc * 4;
    u32x2 v;
    v[0] = pkbf(acc[ct][0], acc[ct][1]);
    v[1] = pkbf(acc[ct][2], acc[ct][3]);
    *reinterpret_cast<u32x2*>(hp) = v;
  }
}

// ---------- R8 gemm (in-kernel W convert) — fallback when ws lacks Wt room ----------
__global__ __launch_bounds__(256) void gemm_xw_ns2(const float* __restrict__ x,
                                                   const float* __restrict__ W,
                                                   __hip_bfloat16* __restrict__ h) {
  __shared__ __hip_bfloat16 Wl[D][D + 8];
  int tid = threadIdx.x;
  for (int i = tid; i < D * D; i += 256) {
    int k = i >> 7, c = i & 127;
    Wl[c][k] = __float2bfloat16(W[i]);
  }
  __syncthreads();

  int wid = tid >> 6, lane = tid & 63;
  int c16 = lane & 15;
  int kc = lane >> 4;

  const int ntiles = NN / 16;
  for (int t = blockIdx.x * 4 + wid; t < ntiles; t += gridDim.x * 4) {
    int r0 = t * 16;
    const float* xrow = x + (size_t)(r0 + c16) * D + kc * 8;
    short8 a[4];
#pragma unroll
    for (int kk = 0; kk < 4; ++kk) {
      float4 f0 = *reinterpret_cast<const float4*>(xrow + kk * 32);
      float4 f1 = *reinterpret_cast<const float4*>(xrow + kk * 32 + 4);
      a[kk][0] = f2bs(f0.x); a[kk][1] = f2bs(f0.y);
      a[kk][2] = f2bs(f0.z); a[kk][3] = f2bs(f0.w);
      a[kk][4] = f2bs(f1.x); a[kk][5] = f2bs(f1.y);
      a[kk][6] = f2bs(f1.z); a[kk][7] = f2bs(f1.w);
    }

    f32x4 acc[8];
#pragma unroll
    for (int ct = 0; ct < 8; ++ct) acc[ct] = (f32x4)(0.0f);

#pragma unroll
    for (int kk = 0; kk < 4; ++kk) {
#pragma unroll
      for (int ct = 0; ct < 8; ++ct) {
        short8 b = *reinterpret_cast<const short8*>(&Wl[ct * 16 + c16][kk * 32 + kc * 8]);
        acc[ct] = __builtin_amdgcn_mfma_f32_16x16x32_bf16(a[kk], b, acc[ct], 0, 0, 0);
      }
    }

    int rbase = r0 + kc * 4;
#pragma unroll
    for (int ct = 0; ct < 8; ++ct) {
      size_t sb = (size_t)(ct >> 2) * NN;
      int cc = (ct & 3) * 16 + c16;
#pragma unroll
      for (int j = 0; j < 4; ++j) {
        h[(sb + (rbase + j)) * 64 + cc] = __float2bfloat16(acc[ct][j]);
      }
    }
  }
}

// ---------- Kernel 2: out[n][s*64..] = (1/16)*sum_e h[s][idx[e]][:] + bias ----------
// FROZEN R8 agg_ns2b: at the ~3.9TB/s TCC fill wall.
__global__ __launch_bounds__(256) void agg_ns2b(const __hip_bfloat16* __restrict__ h,
                                                const int* __restrict__ ptr,
                                                const int* __restrict__ idx,
                                                const float* __restrict__ bias,
                                                float* __restrict__ out) {
  int s = blockIdx.x & 1;
  int g = blockIdx.x >> 1;
  int wv = threadIdx.x >> 6;
  int lane = threadIdx.x & 63;
  int n0 = g * 16 + wv * 4;
  if (n0 >= NN) return;
  int sub = lane & 7;
  int nd = (lane >> 3) & 3;
  int ep = lane >> 5;
  const size_t sbase = (size_t)s * NN;

  int pv = (lane <= 4) ? ptr[n0 + lane] : 0;
  bool fast = __all(lane > 4 || pv == 16 * (n0 + lane));

  if (fast) {
    int iv = __builtin_nontemporal_load(idx + (size_t)n0 * 16 + lane);
    int rid[8];
#pragma unroll
    for (int t = 0; t < 8; ++t) rid[t] = __shfl(iv, nd * 16 + 2 * t + ep);
    short8 v[8];
#pragma unroll
    for (int t = 0; t < 8; ++t)
      v[t] = *reinterpret_cast<const short8*>(h + (sbase + rid[t]) * 64 + sub * 8);

    float acc[8];
#pragma unroll
    for (int q = 0; q < 8; ++q) acc[q] = 0.f;
#pragma unroll
    for (int t = 0; t < 8; ++t)
#pragma unroll
      for (int q = 0; q < 8; ++q) acc[q] += bf2f(v[t][q]);

#pragma unroll
    for (int q = 0; q < 8; ++q) acc[q] += __shfl_xor(acc[q], 32);

    if (ep == 0) {
      const float inv = 1.0f / 16.0f;
      const float* bp = bias + s * 64 + sub * 8;
      float4 b0 = *reinterpret_cast<const float4*>(bp);
      float4 b1 = *reinterpret_cast<const float4*>(bp + 4);
      f32x4 r0, r1;
      r0[0] = fmaf(acc[0], inv, b0.x);
      r0[1] = fmaf(acc[1], inv, b0.y);
      r0[2] = fmaf(acc[2], inv, b0.z);
      r0[3] = fmaf(acc[3], inv, b0.w);
      r1[0] = fmaf(acc[4], inv, b1.x);
      r1[1] = fmaf(acc[5], inv, b1.y);
      r1[2] = fmaf(acc[6], inv, b1.z);
      r1[3] = fmaf(acc[7], inv, b1.w);
      f32x4* op = (f32x4*)(out + (size_t)(n0 + nd) * D + s * 64 + sub * 8);
      __builtin_nontemporal_store(r0, op);
      __builtin_nontemporal_store(r1, op + 1);
    }
  } else {
    for (int nl = 0; nl < 4; ++nl) {
      int node = n0 + nl;
      int p0 = ptr[node], p1 = ptr[node + 1];
      float a = 0.f;
      for (int e = p0; e < p1; ++e) {
        int rid = idx[e];
        a += __bfloat162float(h[(sbase + rid) * 64 + lane]);
      }
      int deg = p1 - p0;
      float invd = deg > 0 ? 1.0f / (float)deg : 0.f;
      int c = s * 64 + lane;
      out[(size_t)node * D + c] = fmaf(a, invd, bias[c]);
    }
  }
}

// ---------- Fallback path (no ws): fp32 agg + fp32 rowgemm ----------
__global__ __launch_bounds__(256) void agg_x(const float* __restrict__ x,
                                             const int* __restrict__ ptr,
                                             const int* __restrict__ idx,
                                             float* __restrict__ out) {
  int node = blockIdx.x * 4 + (threadIdx.x >> 6);
  int lane = threadIdx.x & 63;
  if (node >= NN) return;
  int p0 = ptr[node], p1 = ptr[node + 1];
  float sx = 0.f, sy = 0.f;
  for (int e = p0; e < p1; ++e) {
    int nid = idx[e];
    const float2 v = ((const float2*)(x + (size_t)nid * D))[lane];
    sx += v.x;
    sy += v.y;
  }
  int deg = p1 - p0;
  float inv = (deg > 0) ? (1.0f / (float)deg) : 0.0f;
  float2 r;
  r.x = sx * inv;
  r.y = sy * inv;
  ((float2*)(out + (size_t)node * D))[lane] = r;
}

__global__ __launch_bounds__(256) void rowgemm_inplace(float* __restrict__ io,
                                                       const float* __restrict__ W,
                                                       const float* __restrict__ bias) {
  __shared__ float4 Wl[D * 32];
  __shared__ float xr[8][D];
  int tid = threadIdx.x;
  for (int i = tid; i < D * 32; i += 256) Wl[i] = ((const float4*)W)[i];
  int r = tid >> 5;
  int c4 = tid & 31;
  float4 b4 = ((const float4*)bias)[c4];
  __syncthreads();
  const int ngroups = NN / 8;
  for (int g = blockIdx.x; g < ngroups; g += gridDim.x) {
    size_t base = (size_t)g * 8;
    ((float4*)xr)[tid] = ((const float4*)(io + base * D))[tid];
    __syncthreads();
    float4 acc = b4;
#pragma unroll 8
    for (int k = 0; k < D; ++k) {
      float xv = xr[r][k];
      float4 w = Wl[k * 32 + c4];
      acc.x = fmaf(xv, w.x, acc.x);
      acc.y = fmaf(xv, w.y, acc.y);
      acc.z = fmaf(xv, w.z, acc.z);
      acc.w = fmaf(xv, w.w, acc.w);
    }
    ((float4*)(io + (base + (size_t)r) * D))[c4] = acc;
    __syncthreads();
  }
}

extern "C" void kernel_launch(void* const* d_in, const int* in_sizes, int n_in,
                              void* d_out, int out_size, void* d_ws, size_t ws_size,
                              hipStream_t stream) {
  const float* x = (const float*)d_in[0];
  const float* W = (const float*)d_in[1];
  const float* bias = (const float*)d_in[2];
  const int* ptr = (const int*)d_in[3];
  const int* idx = (const int*)d_in[4];
  float* out = (float*)d_out;

  const size_t need_h = (size_t)NN * D * sizeof(__hip_bfloat16);        // 25.6 MB
  const size_t need_full = need_h + (size_t)D * D * sizeof(__hip_bfloat16);  // +32 KB

  if (ws_size >= need_full) {
    __hip_bfloat16* h = (__hip_bfloat16*)d_ws;
    __hip_bfloat16* Wt = (__hip_bfloat16*)((char*)d_ws + need_h);
    cvt_w<<<64, 256, 0, stream>>>(W, Wt);
    gemm_xw_swp<<<1563, 256, 0, stream>>>(x, Wt, h);
    agg_ns2b<<<(NN / 16) * 2, 256, 0, stream>>>(h, ptr, idx, bias, out);
  } else if (ws_size >= need_h) {
    __hip_bfloat16* h = (__hip_bfloat16*)d_ws;
    gemm_xw_ns2<<<782, 256, 0, stream>>>(x, W, h);
    agg_ns2b<<<(NN / 16) * 2, 256, 0, stream>>>(h, ptr, idx, bias, out);
  } else {
    agg_x<<<NN / 4, 256, 0, stream>>>(x, ptr, idx, out);
    rowgemm_inplace<<<1280, 256, 0, stream>>>(out, W, bias);
  }
}

// Round 13
// 75.510 us; speedup vs baseline: 1.0383x; 1.0383x over previous
//
#include <hip/hip_runtime.h>
#include <hip/hip_bf16.h>

// GCN conv: out = mean-aggregate(h over CSR) + bias, h = x @ W (bf16).
// R12: agg_ns2b frozen (3.9TB/s TCC fill wall, FETCH=147MB = ~100MB
// compulsory + ~47MB L2-capacity (12.8MB slice > 4MiB L2); closing it needs
// sort/combine traffic > saving). gemm: R10-best config (1563 blocks,
// unswapped epilogue) with in-kernel W convert (R2/R8-proven) -> drops the
// cvt_w launch. R11's swap epilogue reverted (measured -2.7us).

#define NN 100000
#define D 128

using short8 = __attribute__((ext_vector_type(8))) short;
using f32x4 = __attribute__((ext_vector_type(4))) float;

__device__ __forceinline__ float bf2f(short s) {
  unsigned int u = ((unsigned int)(unsigned short)s) << 16;
  return __builtin_bit_cast(float, u);
}
__device__ __forceinline__ short f2bs(float f) {
  __hip_bfloat16 b = __float2bfloat16(f);
  return *reinterpret_cast<short*>(&b);
}

// ---------- Kernel 1: h[s][n][c] = (x@W)[n][s*64+c], bf16, 2-slice layout ----------
// 1 tile (16 nodes) per wave; 4 waves/block; 1563 blocks cover 6250 tiles.
// W staged + converted in-kernel (64 scalar iters/thread; measured equal to
// pre-converted staging, R9).
__global__ __launch_bounds__(256) void gemm_xw_r12(const float* __restrict__ x,
                                                   const float* __restrict__ W,
                                                   __hip_bfloat16* __restrict__ h) {
  __shared__ __hip_bfloat16 Wl[D][D + 8];  // Wl[col][k], +8 pad
  int tid = threadIdx.x;
  for (int i = tid; i < D * D; i += 256) {
    int k = i >> 7, c = i & 127;
    Wl[c][k] = __float2bfloat16(W[i]);
  }
  __syncthreads();

  int wid = tid >> 6, lane = tid & 63;
  int c16 = lane & 15;
  int kc = lane >> 4;

  const int ntiles = NN / 16;  // 6250 exact
  int t = blockIdx.x * 4 + wid;
  if (t >= ntiles) return;
  int r0 = t * 16;

  const float* xrow = x + (size_t)(r0 + c16) * D + kc * 8;
  short8 a[4];
#pragma unroll
  for (int kk = 0; kk < 4; ++kk) {
    float4 f0 = *reinterpret_cast<const float4*>(xrow + kk * 32);
    float4 f1 = *reinterpret_cast<const float4*>(xrow + kk * 32 + 4);
    a[kk][0] = f2bs(f0.x); a[kk][1] = f2bs(f0.y);
    a[kk][2] = f2bs(f0.z); a[kk][3] = f2bs(f0.w);
    a[kk][4] = f2bs(f1.x); a[kk][5] = f2bs(f1.y);
    a[kk][6] = f2bs(f1.z); a[kk][7] = f2bs(f1.w);
  }

  f32x4 acc[8];
#pragma unroll
  for (int ct = 0; ct < 8; ++ct) acc[ct] = (f32x4)(0.0f);

#pragma unroll
  for (int kk = 0; kk < 4; ++kk) {
#pragma unroll
    for (int ct = 0; ct < 8; ++ct) {
      short8 b = *reinterpret_cast<const short8*>(&Wl[ct * 16 + c16][kk * 32 + kc * 8]);
      acc[ct] = __builtin_amdgcn_mfma_f32_16x16x32_bf16(a[kk], b, acc[ct], 0, 0, 0);
    }
  }

  // C/D: col = ct*16 + c16, row = kc*4 + j. Slice s = ct>>2, in-slice col (ct&3)*16+c16.
  int rbase = r0 + kc * 4;
#pragma unroll
  for (int ct = 0; ct < 8; ++ct) {
    size_t sb = (size_t)(ct >> 2) * NN;
    int cc = (ct & 3) * 16 + c16;
#pragma unroll
    for (int j = 0; j < 4; ++j) {
      h[(sb + (rbase + j)) * 64 + cc] = __float2bfloat16(acc[ct][j]);
    }
  }
}

// ---------- Kernel 2: out[n][s*64..] = (1/16)*sum_e h[s][idx[e]][:] + bias ----------
// FROZEN R8 agg_ns2b: at the ~3.9TB/s TCC fill wall.
__global__ __launch_bounds__(256) void agg_ns2b(const __hip_bfloat16* __restrict__ h,
                                                const int* __restrict__ ptr,
                                                const int* __restrict__ idx,
                                                const float* __restrict__ bias,
                                                float* __restrict__ out) {
  int s = blockIdx.x & 1;
  int g = blockIdx.x >> 1;
  int wv = threadIdx.x >> 6;
  int lane = threadIdx.x & 63;
  int n0 = g * 16 + wv * 4;
  if (n0 >= NN) return;
  int sub = lane & 7;
  int nd = (lane >> 3) & 3;
  int ep = lane >> 5;
  const size_t sbase = (size_t)s * NN;

  int pv = (lane <= 4) ? ptr[n0 + lane] : 0;
  bool fast = __all(lane > 4 || pv == 16 * (n0 + lane));

  if (fast) {
    int iv = __builtin_nontemporal_load(idx + (size_t)n0 * 16 + lane);
    int rid[8];
#pragma unroll
    for (int t = 0; t < 8; ++t) rid[t] = __shfl(iv, nd * 16 + 2 * t + ep);
    short8 v[8];
#pragma unroll
    for (int t = 0; t < 8; ++t)
      v[t] = *reinterpret_cast<const short8*>(h + (sbase + rid[t]) * 64 + sub * 8);

    float acc[8];
#pragma unroll
    for (int q = 0; q < 8; ++q) acc[q] = 0.f;
#pragma unroll
    for (int t = 0; t < 8; ++t)
#pragma unroll
      for (int q = 0; q < 8; ++q) acc[q] += bf2f(v[t][q]);

#pragma unroll
    for (int q = 0; q < 8; ++q) acc[q] += __shfl_xor(acc[q], 32);

    if (ep == 0) {
      const float inv = 1.0f / 16.0f;
      const float* bp = bias + s * 64 + sub * 8;
      float4 b0 = *reinterpret_cast<const float4*>(bp);
      float4 b1 = *reinterpret_cast<const float4*>(bp + 4);
      f32x4 r0, r1;
      r0[0] = fmaf(acc[0], inv, b0.x);
      r0[1] = fmaf(acc[1], inv, b0.y);
      r0[2] = fmaf(acc[2], inv, b0.z);
      r0[3] = fmaf(acc[3], inv, b0.w);
      r1[0] = fmaf(acc[4], inv, b1.x);
      r1[1] = fmaf(acc[5], inv, b1.y);
      r1[2] = fmaf(acc[6], inv, b1.z);
      r1[3] = fmaf(acc[7], inv, b1.w);
      f32x4* op = (f32x4*)(out + (size_t)(n0 + nd) * D + s * 64 + sub * 8);
      __builtin_nontemporal_store(r0, op);
      __builtin_nontemporal_store(r1, op + 1);
    }
  } else {
    for (int nl = 0; nl < 4; ++nl) {
      int node = n0 + nl;
      int p0 = ptr[node], p1 = ptr[node + 1];
      float a = 0.f;
      for (int e = p0; e < p1; ++e) {
        int rid = idx[e];
        a += __bfloat162float(h[(sbase + rid) * 64 + lane]);
      }
      int deg = p1 - p0;
      float invd = deg > 0 ? 1.0f / (float)deg : 0.f;
      int c = s * 64 + lane;
      out[(size_t)node * D + c] = fmaf(a, invd, bias[c]);
    }
  }
}

// ---------- Fallback path (no ws): fp32 agg + fp32 rowgemm ----------
__global__ __launch_bounds__(256) void agg_x(const float* __restrict__ x,
                                             const int* __restrict__ ptr,
                                             const int* __restrict__ idx,
                                             float* __restrict__ out) {
  int node = blockIdx.x * 4 + (threadIdx.x >> 6);
  int lane = threadIdx.x & 63;
  if (node >= NN) return;
  int p0 = ptr[node], p1 = ptr[node + 1];
  float sx = 0.f, sy = 0.f;
  for (int e = p0; e < p1; ++e) {
    int nid = idx[e];
    const float2 v = ((const float2*)(x + (size_t)nid * D))[lane];
    sx += v.x;
    sy += v.y;
  }
  int deg = p1 - p0;
  float inv = (deg > 0) ? (1.0f / (float)deg) : 0.0f;
  float2 r;
  r.x = sx * inv;
  r.y = sy * inv;
  ((float2*)(out + (size_t)node * D))[lane] = r;
}

__global__ __launch_bounds__(256) void rowgemm_inplace(float* __restrict__ io,
                                                       const float* __restrict__ W,
                                                       const float* __restrict__ bias) {
  __shared__ float4 Wl[D * 32];
  __shared__ float xr[8][D];
  int tid = threadIdx.x;
  for (int i = tid; i < D * 32; i += 256) Wl[i] = ((const float4*)W)[i];
  int r = tid >> 5;
  int c4 = tid & 31;
  float4 b4 = ((const float4*)bias)[c4];
  __syncthreads();
  const int ngroups = NN / 8;
  for (int g = blockIdx.x; g < ngroups; g += gridDim.x) {
    size_t base = (size_t)g * 8;
    ((float4*)xr)[tid] = ((const float4*)(io + base * D))[tid];
    __syncthreads();
    float4 acc = b4;
#pragma unroll 8
    for (int k = 0; k < D; ++k) {
      float xv = xr[r][k];
      float4 w = Wl[k * 32 + c4];
      acc.x = fmaf(xv, w.x, acc.x);
      acc.y = fmaf(xv, w.y, acc.y);
      acc.z = fmaf(xv, w.z, acc.z);
      acc.w = fmaf(xv, w.w, acc.w);
    }
    ((float4*)(io + (base + (size_t)r) * D))[c4] = acc;
    __syncthreads();
  }
}

extern "C" void kernel_launch(void* const* d_in, const int* in_sizes, int n_in,
                              void* d_out, int out_size, void* d_ws, size_t ws_size,
                              hipStream_t stream) {
  const float* x = (const float*)d_in[0];
  const float* W = (const float*)d_in[1];
  const float* bias = (const float*)d_in[2];
  const int* ptr = (const int*)d_in[3];
  const int* idx = (const int*)d_in[4];
  float* out = (float*)d_out;

  const size_t need_h = (size_t)NN * D * sizeof(__hip_bfloat16);  // 25.6 MB

  if (ws_size >= need_h) {
    __hip_bfloat16* h = (__hip_bfloat16*)d_ws;
    gemm_xw_r12<<<1563, 256, 0, stream>>>(x, W, h);
    agg_ns2b<<<(NN / 16) * 2, 256, 0, stream>>>(h, ptr, idx, bias, out);
  } else {
    agg_x<<<NN / 4, 256, 0, stream>>>(x, ptr, idx, out);
    rowgemm_inplace<<<1280, 256, 0, stream>>>(out, W, bias);
  }
}